// Round 12
// baseline (972.911 us; speedup 1.0000x reference)
//
#include <hip/hip_runtime.h>

#define NLAYER 4
#define M_TOK 32768

typedef unsigned short u16;
typedef __bf16 bf16x8 __attribute__((ext_vector_type(8)));
typedef float f32x4 __attribute__((ext_vector_type(4)));

__device__ inline float bf2f(u16 u) {
    union { unsigned int i; float f; } x; x.i = ((unsigned int)u) << 16; return x.f;
}
__device__ inline u16 f2bf(float f) {
    union { float f; unsigned int i; } x; x.f = f;
    return (u16)((x.i + 0x8000u) >> 16);
}
__device__ inline bf16x8 ld_frag(const u16* p) {
    union { uint4 u; bf16x8 b; } c; c.u = *(const uint4*)p; return c.b;
}
__device__ inline unsigned pk2(float a, float b) {
    union { float f; unsigned i; } ua, ub; ua.f = a; ub.f = b;
    return __builtin_amdgcn_perm(ub.i + 0x8000u, ua.i + 0x8000u, 0x07060302u);
}
__device__ inline float gelu_f(float x) {
    float z = 0.7978845608028654f * (x + 0.044715f * x * x * x);
    float t = 1.f - 2.f / (__expf(2.f * z) + 1.f);
    return 0.5f * x * (1.f + t);
}
__device__ inline void gload_lds16(const u16* g, u16* l) {
    __builtin_amdgcn_global_load_lds(
        (const __attribute__((address_space(1))) unsigned int*)g,
        (__attribute__((address_space(3))) unsigned int*)l, 16, 0, 0);
}

#define BAR()   asm volatile("s_barrier" ::: "memory")
#define WAIT8() asm volatile("s_waitcnt vmcnt(8)" ::: "memory")
#define WAIT4() asm volatile("s_waitcnt vmcnt(4)" ::: "memory")
#define WAIT2() asm volatile("s_waitcnt vmcnt(2)" ::: "memory")
#define WAIT0() asm volatile("s_waitcnt vmcnt(0)" ::: "memory")
#define LGKM0() asm volatile("s_waitcnt lgkmcnt(0)" ::: "memory")

// ---------------- dtype sniff ----------------
__global__ void sniff_kernel(const u16* __restrict__ raw, int* __restrict__ flag)
{
    if (threadIdx.x == 0 && blockIdx.x == 0) {
        int ok = 1;
        for (int i = 0; i < 32; i++) {
            u16 u = raw[i];
            int e = (u >> 7) & 0xFF;
            if (!(u == 0 || (e >= 90 && e <= 140))) ok = 0;
        }
        *flag = ok;
    }
}

// ---------------- single-launch ingest ----------------
struct IngestArgs { const void* src[20]; int off[21]; };
__global__ __launch_bounds__(256) void ingest_all(
    IngestArgs a, float* __restrict__ dst, const int* __restrict__ flag, int tot)
{
    int gid = blockIdx.x * 256 + threadIdx.x;
    if (gid >= tot) return;
    int lo = 0, hi = 20;
    while (hi - lo > 1) { int mid = (lo + hi) >> 1; if (gid >= a.off[mid]) lo = mid; else hi = mid; }
    int local = gid - a.off[lo];
    if (*flag) dst[gid] = bf2f(((const u16*)a.src[lo])[local]);
    else       dst[gid] = ((const float*)a.src[lo])[local];
}

// ---------------- weight packing ----------------
__global__ __launch_bounds__(256) void pack_qkv(
    const float* __restrict__ wq, const float* __restrict__ wk, const float* __restrict__ wv,
    const float* __restrict__ bq, const float* __restrict__ bk, const float* __restrict__ bv,
    u16* __restrict__ wT, float* __restrict__ bT)
{
    int l = blockIdx.y;
    int idx = blockIdx.x * 256 + threadIdx.x;
    int n = idx >> 8, k = idx & 255;
    const float* w = (n < 256) ? wq : (n < 512) ? wk : wv;
    int nn = n & 255;
    wT[(size_t)l * 768 * 256 + idx] = f2bf(w[(size_t)l * 65536 + k * 256 + nn]);
    if (idx < 768) {
        const float* bb = (idx < 256) ? bq : (idx < 512) ? bk : bv;
        bT[l * 768 + idx] = bb[l * 256 + (idx & 255)];
    }
}

__global__ __launch_bounds__(256) void pack_t(
    const float* __restrict__ src, u16* __restrict__ dst, int R, int C)
{
    int l = blockIdx.y;
    int idx = blockIdx.x * 256 + threadIdx.x;
    int c = idx / R, r = idx % R;
    size_t base = (size_t)l * R * C;
    dst[base + idx] = f2bf(src[base + (size_t)r * C + c]);
}

// ---------------- embedding + fused layer-0 LN1 ----------------
__global__ __launch_bounds__(256) void embed_ln(
    const int* __restrict__ ids, const float* __restrict__ emb,
    const float* __restrict__ g, const float* __restrict__ b,
    float* __restrict__ x, u16* __restrict__ h)
{
    int t = blockIdx.x * 256 + threadIdx.x;
    int row = t >> 6, c = (t & 63) * 4;
    int id = ids[row];
    float4 e = *(const float4*)(emb + (size_t)id * 256 + c);
    *(float4*)(x + (size_t)row * 256 + c) = e;
    float s = e.x + e.y + e.z + e.w;
    float s2 = e.x * e.x + e.y * e.y + e.z * e.z + e.w * e.w;
    #pragma unroll
    for (int mk = 1; mk < 64; mk <<= 1) {
        s += __shfl_xor(s, mk, 64);
        s2 += __shfl_xor(s2, mk, 64);
    }
    float mean = s * (1.f / 256.f);
    float var = s2 * (1.f / 256.f) - mean * mean;
    float rstd = rsqrtf(var + 1e-5f);
    float4 gg = *(const float4*)(g + c);
    float4 bb = *(const float4*)(b + c);
    union { unsigned long long u; u16 q[4]; } oo;
    oo.q[0] = f2bf((e.x - mean) * rstd * gg.x + bb.x);
    oo.q[1] = f2bf((e.y - mean) * rstd * gg.y + bb.y);
    oo.q[2] = f2bf((e.z - mean) * rstd * gg.z + bb.z);
    oo.q[3] = f2bf((e.w - mean) * rstd * gg.w + bb.w);
    *(unsigned long long*)(h + (size_t)row * 256 + c) = oo.u;
}

// ---------------- GEMM: 128x128 tile, BK=32, 4-slot ring, ONE barrier per chunk ----------------
// Final isolation experiment: R11 (BK=64, 2 bar/chunk) showed event-halving with byte-doubling
// is ~null; this holds bytes/occupancy constant and removes the trailing LGKM0+BAR instead.
// Safety (R6-fix argument reversed): slot c&3 is restaged in iter c+2; the restager cannot
// pass BAR(c+1) until every reader of iter c has arrived there, and arrival implies all
// CHUNK(c) MFMAs issued => compiler lgkm waits executed => ds_reads complete. Stage-ahead 2,
// counted WAIT8/4/0. LDS 64 KB -> 2 blocks/CU.
template <int EPI, int K>
__global__ __launch_bounds__(256, 2) void gemm_db(
    const u16* __restrict__ A, const u16* __restrict__ Bt, const float* __restrict__ bias,
    u16* __restrict__ outB, float* __restrict__ resid, int N)
{
    __shared__ u16 lds[32768];   // 4 slots x 8192 u16 (A 0..4095 | B 4096..8191)
    constexpr int NC = K / 32;
    int tid = threadIdx.x, lane = tid & 63, wave = tid >> 6;
    int col = lane & 15, quad = lane >> 4;
    int wm = (wave >> 1) * 64, wn = (wave & 1) * 64;
    int bm = blockIdx.x * 128, bn = blockIdx.y * 128;

    int rL = wave * 32 + (lane >> 2);
    int sx = (lane & 3) ^ ((lane >> 2) & 3);
    const u16* srcA0 = A + (size_t)(bm + rL) * K + sx * 8;
    const u16* srcB0 = Bt + (size_t)(bn + rL) * K + sx * 8;
    int st = wave * 1024 + lane * 8;

    int g8 = (quad ^ (col & 3)) * 8;
    int aoff = (wm + col) * 32 + g8;
    int boff = (wn + col) * 32 + g8;

    f32x4 z4 = { 0.f, 0.f, 0.f, 0.f };
    f32x4 acc[4][4];
    #pragma unroll
    for (int i = 0; i < 4; i++)
        #pragma unroll
        for (int j = 0; j < 4; j++) acc[i][j] = z4;

    #define STAGE(c) do {                                                \
        u16* _bs = lds + ((c) & 3) * 8192;                               \
        const u16* _a = srcA0 + (c) * 32;                                \
        const u16* _b = srcB0 + (c) * 32;                                \
        gload_lds16(_a, _bs + st);                                       \
        gload_lds16(_a + (size_t)16 * K, _bs + st + 512);                \
        gload_lds16(_b, _bs + 4096 + st);                                \
        gload_lds16(_b + (size_t)16 * K, _bs + 4096 + st + 512);         \
    } while (0)

    #define CHUNK(c) do {                                                \
        const u16* _bs = lds + ((c) & 3) * 8192;                         \
        bf16x8 af[4], bfv[4];                                            \
        _Pragma("unroll")                                                \
        for (int i = 0; i < 4; i++) af[i] = ld_frag(_bs + aoff + i * 512); \
        _Pragma("unroll")                                                \
        for (int j = 0; j < 4; j++) bfv[j] = ld_frag(_bs + 4096 + boff + j * 512); \
        _Pragma("unroll")                                                \
        for (int i = 0; i < 4; i++)                                      \
            _Pragma("unroll")                                            \
            for (int j = 0; j < 4; j++)                                  \
                acc[i][j] = __builtin_amdgcn_mfma_f32_16x16x32_bf16(af[i], bfv[j], acc[i][j], 0, 0, 0); \
    } while (0)

    STAGE(0); STAGE(1);
    #pragma unroll 4
    for (int c = 0; c < NC; ++c) {
        if (c + 2 < NC) STAGE(c + 2);
        int rem = NC - 1 - c;                // chunks staged beyond c
        if (rem >= 2) WAIT8();
        else if (rem == 1) WAIT4();
        else WAIT0();
        BAR();                               // chunk c resident for all waves
        CHUNK(c);                            // no trailing barrier (4-slot WAR-safe)
    }
    __syncthreads();                         // drain before epilogue overwrites lds

    if (EPI == 2) {
        float* Cf = (float*)lds;
        #pragma unroll
        for (int h = 0; h < 2; h++) {
            if ((wave & 1) == h) {
                #pragma unroll
                for (int j = 0; j < 4; j++) {
                    float bv = bias[bn + wn + j * 16 + col];
                    #pragma unroll
                    for (int i = 0; i < 4; i++) {
                        int rl = wm + i * 16 + quad * 4;
                        #pragma unroll
                        for (int r = 0; r < 4; r++)
                            Cf[(rl + r) * 68 + j * 16 + col] = acc[i][j][r] + bv;
                    }
                }
            }
            LGKM0(); BAR();
            #pragma unroll
            for (int u = 0; u < 8; u++) {
                int row = u * 16 + (tid >> 4);
                int cseg = (tid & 15) * 4;
                float* rp = resid + (size_t)(bm + row) * N + bn + h * 64 + cseg;
                const float* cp = Cf + row * 68 + cseg;
                float4 rv = *(float4*)rp;
                float4 cv = *(const float4*)cp;
                rv.x += cv.x; rv.y += cv.y; rv.z += cv.z; rv.w += cv.w;
                *(float4*)rp = rv;
            }
            LGKM0(); BAR();
        }
    } else {
        u16* Cs = lds;
        #pragma unroll
        for (int j = 0; j < 4; j++) {
            int ccl = wn + j * 16 + col;
            float bv = bias[bn + ccl];
            #pragma unroll
            for (int i = 0; i < 4; i++) {
                int rl = wm + i * 16 + quad * 4;
                #pragma unroll
                for (int r = 0; r < 4; r++) {
                    float v = acc[i][j][r] + bv;
                    if (EPI == 1) v = gelu_f(v);
                    Cs[(rl + r) * 136 + ccl] = f2bf(v);
                }
            }
        }
        __syncthreads();
        #pragma unroll
        for (int u = 0; u < 8; u++) {
            int row = u * 16 + (tid >> 4);
            int c8 = (tid & 15) * 8;
            u16* op = outB + (size_t)(bm + row) * N + bn + c8;
            *(uint4*)op = *(const uint4*)(Cs + row * 136 + c8);
        }
    }
    #undef STAGE
    #undef CHUNK
}

// ---------------- fused LN2+MLP with producer/consumer wave specialization + T5 ----------------
// (R10/R11-measured ~102 us; untouched -- single-variable experiment on gemm_db.)
template <int FUSE>
__global__ __launch_bounds__(512, 2) void mlp2s(
    const float* __restrict__ xin, const u16* __restrict__ w1T, const u16* __restrict__ w2T,
    const float* __restrict__ gamma, const float* __restrict__ beta,
    const float* __restrict__ b1, const float* __restrict__ b2, float* __restrict__ xr,
    const float* __restrict__ g1n, const float* __restrict__ b1n, u16* __restrict__ hout)
{
    __shared__ u16 L[77824];
    int tid = threadIdx.x, lane = tid & 63, wave = tid >> 6;
    int col = lane & 15, quad = lane >> 4;
    int g8 = (quad ^ (col & 3)) * 8;
    int bm = blockIdx.x * 128;
    int isProd = (wave < 4);
    int pw = wave & 3;

    {
        int sub = tid & 7, rsel = tid >> 3;
        float4 g4[8], b4[8];
        #pragma unroll
        for (int q = 0; q < 8; q++) {
            g4[q] = *(const float4*)(gamma + sub * 32 + q * 4);
            b4[q] = *(const float4*)(beta  + sub * 32 + q * 4);
        }
        #pragma unroll
        for (int p = 0; p < 2; p++) {
            int row = p * 64 + rsel;
            const float* xp = xin + (size_t)(bm + row) * 256 + sub * 32;
            float4 v4[8];
            #pragma unroll
            for (int q = 0; q < 8; q++) v4[q] = *(const float4*)(xp + q * 4);
            float s1 = 0.f, s2 = 0.f;
            #pragma unroll
            for (int q = 0; q < 8; q++) {
                s1 += v4[q].x + v4[q].y + v4[q].z + v4[q].w;
                s2 += v4[q].x * v4[q].x + v4[q].y * v4[q].y
                    + v4[q].z * v4[q].z + v4[q].w * v4[q].w;
            }
            s1 += __shfl_xor(s1, 1, 64); s2 += __shfl_xor(s2, 1, 64);
            s1 += __shfl_xor(s1, 2, 64); s2 += __shfl_xor(s2, 2, 64);
            s1 += __shfl_xor(s1, 4, 64); s2 += __shfl_xor(s2, 4, 64);
            float mean = s1 * (1.f / 256.f);
            float var  = s2 * (1.f / 256.f) - mean * mean;
            float rstd = rsqrtf(var + 1e-5f);
            #pragma unroll
            for (int j = 0; j < 4; j++) {
                float4 a = v4[2 * j], c = v4[2 * j + 1];
                float4 ga = g4[2 * j], gc = g4[2 * j + 1];
                float4 ba = b4[2 * j], bc = b4[2 * j + 1];
                union { uint4 u; u16 q[8]; } pkv;
                pkv.q[0] = f2bf((a.x - mean) * rstd * ga.x + ba.x);
                pkv.q[1] = f2bf((a.y - mean) * rstd * ga.y + ba.y);
                pkv.q[2] = f2bf((a.z - mean) * rstd * ga.z + ba.z);
                pkv.q[3] = f2bf((a.w - mean) * rstd * ga.w + ba.w);
                pkv.q[4] = f2bf((c.x - mean) * rstd * gc.x + bc.x);
                pkv.q[5] = f2bf((c.y - mean) * rstd * gc.y + bc.y);
                pkv.q[6] = f2bf((c.z - mean) * rstd * gc.z + bc.z);
                pkv.q[7] = f2bf((c.w - mean) * rstd * gc.w + bc.w);
                *(uint4*)(L + sub * 4096 + row * 32 + ((j ^ (row & 3)) * 8)) = pkv.u;
            }
        }
        float2 bv = *(const float2*)(b1 + tid * 2);
        *(float2*)((float*)(L + 75776) + tid * 2) = bv;
    }

    #define STAGE_W1(ff, base) do {                                                  \
        _Pragma("unroll")                                                            \
        for (int gg = 0; gg < 2; gg++) {                                             \
            int u_ = gg * 512 + tid;                                                 \
            int ks_ = u_ >> 7, rowf_ = (u_ & 127) >> 2, s_ = u_ & 3;                 \
            gload_lds16(w1T + (size_t)((ff) * 32 + rowf_) * 256 + ks_ * 32           \
                            + ((s_ ^ (rowf_ & 3)) * 8),                              \
                        L + (base) + u_ * 8);                                        \
        }                                                                            \
    } while (0)

    #define STAGE_W2(ff, base) do {                                                  \
        _Pragma("unroll")                                                            \
        for (int gg = 0; gg < 2; gg++) {                                             \
            int u_ = gg * 512 + tid;                                                 \
            int d_ = u_ >> 2, s_ = u_ & 3;                                           \
            gload_lds16(w2T + (size_t)d_ * 1024 + (ff) * 32 + ((s_ ^ (d_ & 3)) * 8), \
                        L + (base) + u_ * 8);                                        \
        }                                                                            \
    } while (0)

    STAGE_W1(0, 32768);
    WAIT0(); LGKM0(); BAR();

    f32x4 z4 = { 0.f, 0.f, 0.f, 0.f };
    f32x4 acc2[2][16];
    #pragma unroll
    for (int mt = 0; mt < 2; mt++)
        #pragma unroll
        for (int nt = 0; nt < 16; nt++) acc2[mt][nt] = z4;
    const float* b1l = (const float*)(L + 75776);

    #pragma unroll 2
    for (int f = 0; f < 32; ++f) {
        int pc = f & 1, pn = pc ^ 1;
        if (f < 31) STAGE_W1(f + 1, 32768 + pn * 8192);
        STAGE_W2(f, 49152 + pc * 8192);
        if (f == 31) WAIT2(); else WAIT4();
        BAR();

        if (isProd) {
            const u16* w1b = L + 32768 + pc * 8192;
            f32x4 a1[2][2];
            a1[0][0] = z4; a1[0][1] = z4; a1[1][0] = z4; a1[1][1] = z4;
            __builtin_amdgcn_s_setprio(1);
            #pragma unroll
            for (int ks = 0; ks < 8; ks++) {
                bf16x8 hf0 = ld_frag(L + ks * 4096 + (pw * 32 + col) * 32 + g8);
                bf16x8 hf1 = ld_frag(L + ks * 4096 + (pw * 32 + 16 + col) * 32 + g8);
                #pragma unroll
                for (int kt = 0; kt < 2; kt++) {
                    bf16x8 wf = ld_frag(w1b + ks * 1024 + (kt * 16 + col) * 32 + g8);
                    a1[0][kt] = __builtin_amdgcn_mfma_f32_16x16x32_bf16(wf, hf0, a1[0][kt], 0, 0, 0);
                    a1[1][kt] = __builtin_amdgcn_mfma_f32_16x16x32_bf16(wf, hf1, a1[1][kt], 0, 0, 0);
                }
            }
            __builtin_amdgcn_s_setprio(0);
            u16* gd = L + 65536 + pc * 5120;
            #pragma unroll
            for (int mt = 0; mt < 2; mt++)
                #pragma unroll
                for (int kt = 0; kt < 2; kt++) {
                    float4 bv = *(const float4*)(b1l + f * 32 + kt * 16 + quad * 4);
                    float p0 = gelu_f(a1[mt][kt][0] + bv.x);
                    float p1 = gelu_f(a1[mt][kt][1] + bv.y);
                    float p2 = gelu_f(a1[mt][kt][2] + bv.z);
                    float p3 = gelu_f(a1[mt][kt][3] + bv.w);
                    uint2 w; w.x = pk2(p0, p1); w.y = pk2(p2, p3);
                    *(uint2*)(gd + (pw * 32 + mt * 16 + col) * 40 + kt * 16 + quad * 4) = w;
                }
        } else if (f > 0) {
            const u16* gs = L + 65536 + pn * 5120;
            const u16* w2b = L + 49152 + pn * 8192;
            __builtin_amdgcn_s_setprio(1);
            bf16x8 gf0 = ld_frag(gs + (pw * 32 + col) * 40 + quad * 8);
            bf16x8 gf1 = ld_frag(gs + (pw * 32 + 16 + col) * 40 + quad * 8);
            #pragma unroll
            for (int nt = 0; nt < 16; nt++) {
                bf16x8 wf2 = ld_frag(w2b + (nt * 16 + col) * 32 + g8);
                acc2[0][nt] = __builtin_amdgcn_mfma_f32_16x16x32_bf16(gf0, wf2, acc2[0][nt], 0, 0, 0);
                acc2[1][nt] = __builtin_amdgcn_mfma_f32_16x16x32_bf16(gf1, wf2, acc2[1][nt], 0, 0, 0);
            }
            __builtin_amdgcn_s_setprio(0);
        }
        LGKM0(); BAR();
    }

    WAIT0();
    if (!isProd) {
        const u16* gs = L + 65536 + 5120;
        const u16* w2b = L + 49152 + 8192;
        __builtin_amdgcn_s_setprio(1);
        bf16x8 gf0 = ld_frag(gs + (pw * 32 + col) * 40 + quad * 8);
        bf16x8 gf1 = ld_frag(gs + (pw * 32 + 16 + col) * 40 + quad * 8);
        #pragma unroll
        for (int nt = 0; nt < 16; nt++) {
            bf16x8 wf2 = ld_frag(w2b + (nt * 16 + col) * 32 + g8);
            acc2[0][nt] = __builtin_amdgcn_mfma_f32_16x16x32_bf16(gf0, wf2, acc2[0][nt], 0, 0, 0);
            acc2[1][nt] = __builtin_amdgcn_mfma_f32_16x16x32_bf16(gf1, wf2, acc2[1][nt], 0, 0, 0);
        }
        __builtin_amdgcn_s_setprio(0);

        float b2v[16], g1v[16], b1v[16];
        #pragma unroll
        for (int nt = 0; nt < 16; nt++) {
            b2v[nt] = b2[nt * 16 + col];
            if (FUSE) { g1v[nt] = g1n[nt * 16 + col]; b1v[nt] = b1n[nt * 16 + col]; }
        }
        #pragma unroll
        for (int mt = 0; mt < 2; mt++)
            #pragma unroll
            for (int r = 0; r < 4; r++) {
                int m = pw * 32 + mt * 16 + quad * 4 + r;
                float* xrow = xr + (size_t)(bm + m) * 256;
                float s1 = 0.f, s2 = 0.f;
                #pragma unroll
                for (int nt = 0; nt < 16; nt++) {
                    float xv = xrow[nt * 16 + col] + acc2[mt][nt][r] + b2v[nt];
                    acc2[mt][nt][r] = xv;
                    s1 += xv; s2 += xv * xv;
                }
                #pragma unroll
                for (int nt = 0; nt < 16; nt++) xrow[nt * 16 + col] = acc2[mt][nt][r];
                if (FUSE) {
                    s1 += __shfl_xor(s1, 1, 64); s2 += __shfl_xor(s2, 1, 64);
                    s1 += __shfl_xor(s1, 2, 64); s2 += __shfl_xor(s2, 2, 64);
                    s1 += __shfl_xor(s1, 4, 64); s2 += __shfl_xor(s2, 4, 64);
                    s1 += __shfl_xor(s1, 8, 64); s2 += __shfl_xor(s2, 8, 64);
                    float mean = s1 * (1.f / 256.f);
                    float var  = s2 * (1.f / 256.f) - mean * mean;
                    float rstd = rsqrtf(var + 1e-5f);
                    #pragma unroll
                    for (int nt = 0; nt < 16; nt++)
                        L[m * 256 + nt * 16 + col] =
                            f2bf((acc2[mt][nt][r] - mean) * rstd * g1v[nt] + b1v[nt]);
                }
            }
    }
    if (FUSE) {
        LGKM0(); BAR();
        #pragma unroll
        for (int i = 0; i < 8; i++) {
            int flat = i * 4096 + tid * 8;
            *(uint4*)(hout + (size_t)bm * 256 + flat) = *(const uint4*)(L + flat);
        }
    }
    #undef STAGE_W1
    #undef STAGE_W2
}

// ---------------- sliding-window attention, S^T formulation ----------------
__global__ __launch_bounds__(256, 3) void attn_kernel(
    const u16* __restrict__ qkv, u16* __restrict__ attno)
{
    __shared__ u16 Ks[64 * 72];
    __shared__ u16 Vt[64 * 68];
    __shared__ u16 Ps[4 * 16 * 72];
    int g = blockIdx.x;
    int xc = g & 7, t = g >> 3;
    int r12 = t & 15, s8 = t >> 4;
    int ng = s8 * 8 + xc;
    int bb = ng >> 4, nn = ng & 15;
    int hh = r12 & 3, t2 = r12 >> 2;
    int tid = threadIdx.x, lane = tid & 63, wave = tid >> 6;
    int q16 = lane & 15, quad = lane >> 4;
    float slope = exp2f(-2.f * (float)(hh + 1));
    float slopeL = slope * 1.44269504f;
    const float C1 = 0.125f * 1.44269504f;

    int qt0 = t2 * 2;
    size_t tok0 = (size_t)bb * 8192 + nn * 512;

    bf16x8 bqf[2][2];
    {
        int qrow = t2 * 128 + wave * 16 + q16;
        const u16* qp = qkv + (tok0 + qrow) * 768 + hh * 64 + quad * 8;
        bqf[0][0] = ld_frag(qp);
        bqf[0][1] = ld_frag(qp + 32);
        const u16* qp1 = qp + (size_t)64 * 768;
        bqf[1][0] = ld_frag(qp1);
        bqf[1][1] = ld_frag(qp1 + 32);
    }

    f32x4 z4 = { 0.f, 0.f, 0.f, 0.f };
    f32x4 oa[2][4];
    #pragma unroll
    for (int s = 0; s < 2; s++)
        #pragma unroll
        for (int dt = 0; dt < 4; dt++) oa[s][dt] = z4;
    float lsum[2] = { 0.f, 0.f };
    u16* Psw = Ps + wave * (16 * 72);

    int c_lo = (nn == 0) ? 8 : qt0;
    int c_hi = qt0 + 9;

    int kkK = tid >> 3, c8k = (tid & 7) * 8;
    int kk2 = (tid & 31) * 2, c8v = (tid >> 5) * 8;

    uint4 pk0, pk1, pv0, pv1;
    auto load_c = [&](int c) {
        int tok = (int)tok0 - 512 + c * 64;
        const u16* bK = qkv + (size_t)(tok + kkK) * 768 + hh * 64 + 256 + c8k;
        pk0 = *(const uint4*)bK;
        pk1 = *(const uint4*)(bK + (size_t)32 * 768);
        const u16* bV = qkv + (size_t)(tok + kk2) * 768 + hh * 64 + 512 + c8v;
        pv0 = *(const uint4*)bV;
        pv1 = *(const uint4*)(bV + 768);
    };
    load_c(c_lo);

    for (int c = c_lo; c <= c_hi; ++c) {
        LGKM0(); BAR();
        *(uint4*)(Ks + kkK * 72 + c8k) = pk0;
        *(uint4*)(Ks + (kkK + 32) * 72 + c8k) = pk1;
        {
            union { uint4 u; u16 s[8]; } a, b;
            a.u = pv0; b.u = pv1;
            #pragma unroll
            for (int j = 0; j < 8; j++) {
                unsigned w = (unsigned)a.s[j] | ((unsigned)b.s[j] << 16);
                *(unsigned*)(Vt + (c8v + j) * 68 + kk2) = w;
            }
        }
        if (c < c_hi) load_c(c + 1);
        LGKM0(); BAR();

        bf16x8 kf[4][2];
        #pragma unroll
        for (int kt = 0; kt < 4; kt++)
            #pragma unroll
            for (int ks = 0; ks < 2; ks++)
                kf[kt][ks] = ld_frag(Ks + (kt * 16 + q16) * 72 + ks * 32 + quad * 8);
        bf16x8 vf[4][2];
        #pragma unroll
        for (int dt = 0; dt < 4; dt++)
            #pragma unroll
            for (int ks = 0; ks < 2; ks++) {
                union { uint2 p[2]; bf16x8 b; } cv;
                const u16* vp = Vt + (dt * 16 + q16) * 68 + ks * 32 + quad * 8;
                cv.p[0] = *(const uint2*)(vp);
                cv.p[1] = *(const uint2*)(vp + 4);
                vf[dt][ks] = cv.b;
            }

        int act0 = (c <= qt0 + 8);
        int act1 = (c >= qt0 + 1);
        #pragma unroll
        for (int s = 0; s < 2; s++) {
            if (s == 0 ? !act0 : !act1) continue;
            f32x4 st[4];
            #pragma unroll
            for (int kt = 0; kt < 4; kt++) {
                f32x4 z = z4;
                #pragma unroll
                for (int ks = 0; ks < 2; ks++)
                    z = __builtin_amdgcn_mfma_f32_16x16x32_bf16(kf[kt][ks], bqf[s][ks], z, 0, 0, 0);
                st[kt] = z;
            }
            int qg = t2 * 128 + s * 64 + wave * 16 + q16;
            int D = 512 + qg - c * 64 - quad * 4;
            float nb = -slopeL * (float)D;
            int qts = qt0 + s;
            int diag = (c == qts) || (c == qts + 8);
            float ls = 0.f;
            #pragma unroll
            for (int kt = 0; kt < 4; kt++) {
                float pk[4];
                #pragma unroll
                for (int r = 0; r < 4; r++) {
                    float bias = fmaf(slopeL, (float)(kt * 16 + r), nb);
                    float p = exp2f(fmaf(st[kt][r], C1, bias));
                    if (diag) {
                        int dd = D - (kt * 16 + r);
                        p = ((unsigned)dd <= 512u) ? p : 0.f;
                    }
                    ls += p; pk[r] = p;
                }
                uint2 w;
                w.x = pk2(pk[0], pk[1]);
                w.y = pk2(pk[2], pk[3]);
                *(uint2*)(Psw + q16 * 72 + kt * 16 + quad * 4) = w;
            }
            lsum[s] += ls;
            bf16x8 pf[2];
            #pragma unroll
            for (int ks = 0; ks < 2; ks++)
                pf[ks] = ld_frag(Psw + q16 * 72 + ks * 32 + quad * 8);
            #pragma unroll
            for (int dt = 0; dt < 4; dt++)
                #pragma unroll
                for (int ks = 0; ks < 2; ks++)
                    oa[s][dt] = __builtin_amdgcn_mfma_f32_16x16x32_bf16(pf[ks], vf[dt][ks], oa[s][dt], 0, 0, 0);
        }
    }

    #pragma unroll
    for (int s = 0; s < 2; s++) {
        float lr = lsum[s];
        lr += __shfl_xor(lr, 16, 64);
        lr += __shfl_xor(lr, 32, 64);
        lsum[s] = lr;
    }
    float* lx = (float*)Psw;
    if (quad == 0) { lx[q16] = lsum[0]; lx[16 + q16] = lsum[1]; }
    #pragma unroll
    for (int s = 0; s < 2; s++) {
        float4 lq = *(const float4*)(lx + s * 16 + quad * 4);
        float inv[4] = { 1.f / lq.x, 1.f / lq.y, 1.f / lq.z, 1.f / lq.w };
        int tokb = (int)tok0 + t2 * 128 + s * 64 + wave * 16 + quad * 4;
        #pragma unroll
        for (int r = 0; r < 4; r++)
            #pragma unroll
            for (int dt = 0; dt < 4; dt++)
                attno[(size_t)(tokb + r) * 256 + hh * 64 + dt * 16 + q16] = f2bf(oa[s][dt][r] * inv[r]);
    }
}

// ---------------- LM head with fused final layernorm ----------------
__global__ __launch_bounds__(256) void head_ln_kernel(
    const float* __restrict__ x, const float* __restrict__ g, const float* __restrict__ b,
    const float* __restrict__ hw, const int* __restrict__ flag,
    u16* __restrict__ outb, float* __restrict__ outf)
{
    __shared__ float Wt[14 * 256];
    int tid = threadIdx.x;
    for (int i = tid; i < 14 * 256; i += 256) {
        int v = i >> 8, d = i & 255;
        Wt[i] = hw[d * 14 + v];
    }
    __syncthreads();
    int wave = tid >> 6, lane = tid & 63;
    int row = blockIdx.x * 4 + wave;
    float4 v = *(const float4*)(x + (size_t)row * 256 + lane * 4);
    float s = v.x + v.y + v.z + v.w;
    float s2 = v.x * v.x + v.y * v.y + v.z * v.z + v.w * v.w;
    #pragma unroll
    for (int mk = 1; mk < 64; mk <<= 1) {
        s += __shfl_xor(s, mk, 64);
        s2 += __shfl_xor(s2, mk, 64);
    }
    float mean = s * (1.f / 256.f);
    float var = s2 * (1.f / 256.f) - mean * mean;
    float rstd = rsqrtf(var + 1e-5f);
    int d0 = lane * 4;
    float4 gg = *(const float4*)(g + d0);
    float4 bb = *(const float4*)(b + d0);
    float hv[4];
    hv[0] = (v.x - mean) * rstd * gg.x + bb.x;
    hv[1] = (v.y - mean) * rstd * gg.y + bb.y;
    hv[2] = (v.z - mean) * rstd * gg.z + bb.z;
    hv[3] = (v.w - mean) * rstd * gg.w + bb.w;
    int isbf = *flag;
    for (int vv = 0; vv < 14; vv++) {
        float4 wv4 = *(const float4*)(Wt + vv * 256 + lane * 4);
        float sd = hv[0] * wv4.x + hv[1] * wv4.y + hv[2] * wv4.z + hv[3] * wv4.w;
        #pragma unroll
        for (int mk = 1; mk < 64; mk <<= 1) sd += __shfl_xor(sd, mk, 64);
        if (lane == 0) {
            if (isbf) outb[(size_t)row * 14 + vv] = f2bf(sd);
            else      outf[(size_t)row * 14 + vv] = sd;
        }
    }
}

extern "C" void kernel_launch(void* const* d_in, const int* in_sizes, int n_in,
                              void* d_out, int out_size, void* d_ws, size_t ws_size,
                              hipStream_t stream) {
    (void)out_size; (void)ws_size;
    const int* ids = (const int*)d_in[0];

    char* ws = (char*)d_ws;
    int* flag = (int*)ws; ws += 16;

    IngestArgs ia;
    int off = 0;
    for (int i = 1; i < n_in && i <= 20; i++) {
        ia.src[i - 1] = d_in[i];
        ia.off[i - 1] = off;
        off += in_sizes[i];
    }
    ia.off[20] = off;
    float* fbase = (float*)ws;
    ws += (size_t)((off + 3) & ~3) * 4;
    float* fin[21];
    for (int i = 1; i <= 20; i++) fin[i] = fbase + ia.off[i - 1];

    float* x    = (float*)ws;  ws += (size_t)M_TOK * 256 * 4;
    u16* h      = (u16*)ws;    ws += (size_t)M_TOK * 256 * 2;
    u16* qkv    = (u16*)ws;    ws += (size_t)M_TOK * 768 * 2;
    u16* attno  = (u16*)ws;    ws += (size_t)M_TOK * 256 * 2;
    u16* wqkvT  = (u16*)ws;    ws += (size_t)NLAYER * 768 * 256 * 2;
    u16* woT    = (u16*)ws;    ws += (size_t)NLAYER * 256 * 256 * 2;
    u16* w1T    = (u16*)ws;    ws += (size_t)NLAYER * 1024 * 256 * 2;
    u16* w2T    = (u16*)ws;    ws += (size_t)NLAYER * 256 * 1024 * 2;
    float* bqkv = (float*)ws;  ws += (size_t)NLAYER * 768 * 4;

    sniff_kernel<<<1, 64, 0, stream>>>((const u16*)d_in[1], flag);
    ingest_all<<<(off + 255) / 256, 256, 0, stream>>>(ia, fbase, flag, off);

    pack_qkv<<<dim3(768, NLAYER), 256, 0, stream>>>(fin[2], fin[4], fin[6],
                                                    fin[3], fin[5], fin[7], wqkvT, bqkv);
    pack_t<<<dim3(256, NLAYER), 256, 0, stream>>>(fin[8], woT, 256, 256);
    pack_t<<<dim3(1024, NLAYER), 256, 0, stream>>>(fin[14], w1T, 256, 1024);
    pack_t<<<dim3(1024, NLAYER), 256, 0, stream>>>(fin[16], w2T, 1024, 256);

    embed_ln<<<8192, 256, 0, stream>>>(ids, fin[1], fin[10], fin[11], x, h);

    for (int l = 0; l < NLAYER; ++l) {
        gemm_db<0, 256><<<dim3(256, 6), 256, 0, stream>>>(h, wqkvT + (size_t)l * 768 * 256,
                                                          bqkv + l * 768, qkv, nullptr, 768);
        attn_kernel<<<1024, 256, 0, stream>>>(qkv, attno);
        gemm_db<2, 256><<<dim3(256, 2), 256, 0, stream>>>(attno, woT + (size_t)l * 65536,
                                                          fin[9] + l * 256, nullptr, x, 256);
        if (l < NLAYER - 1) {
            mlp2s<1><<<256, 512, 0, stream>>>(x, w1T + (size_t)l * 262144,
                                              w2T + (size_t)l * 262144,
                                              fin[12] + l * 256, fin[13] + l * 256,
                                              fin[15] + l * 1024, fin[17] + l * 256, x,
                                              fin[10] + (l + 1) * 256, fin[11] + (l + 1) * 256, h);
        } else {
            mlp2s<0><<<256, 512, 0, stream>>>(x, w1T + (size_t)l * 262144,
                                              w2T + (size_t)l * 262144,
                                              fin[12] + l * 256, fin[13] + l * 256,
                                              fin[15] + l * 1024, fin[17] + l * 256, x,
                                              fin[10], fin[11], h);
        }
    }
    head_ln_kernel<<<8192, 256, 0, stream>>>(x, fin[18], fin[19], fin[20], flag,
                                             (u16*)d_out, (float*)d_out);
}

// Round 13
// 958.964 us; speedup vs baseline: 1.0145x; 1.0145x over previous
//
#include <hip/hip_runtime.h>

#define NLAYER 4
#define M_TOK 32768

typedef unsigned short u16;
typedef __bf16 bf16x8 __attribute__((ext_vector_type(8)));
typedef float f32x4 __attribute__((ext_vector_type(4)));

__device__ inline float bf2f(u16 u) {
    union { unsigned int i; float f; } x; x.i = ((unsigned int)u) << 16; return x.f;
}
__device__ inline u16 f2bf(float f) {
    union { float f; unsigned int i; } x; x.f = f;
    return (u16)((x.i + 0x8000u) >> 16);
}
__device__ inline bf16x8 ld_frag(const u16* p) {
    union { uint4 u; bf16x8 b; } c; c.u = *(const uint4*)p; return c.b;
}
__device__ inline unsigned pk2(float a, float b) {
    union { float f; unsigned i; } ua, ub; ua.f = a; ub.f = b;
    return __builtin_amdgcn_perm(ub.i + 0x8000u, ua.i + 0x8000u, 0x07060302u);
}
__device__ inline float gelu_f(float x) {
    float z = 0.7978845608028654f * (x + 0.044715f * x * x * x);
    float t = 1.f - 2.f / (__expf(2.f * z) + 1.f);
    return 0.5f * x * (1.f + t);
}
__device__ inline void gload_lds16(const u16* g, u16* l) {
    __builtin_amdgcn_global_load_lds(
        (const __attribute__((address_space(1))) unsigned int*)g,
        (__attribute__((address_space(3))) unsigned int*)l, 16, 0, 0);
}

#define BAR()   asm volatile("s_barrier" ::: "memory")
#define WAIT8() asm volatile("s_waitcnt vmcnt(8)" ::: "memory")
#define WAIT4() asm volatile("s_waitcnt vmcnt(4)" ::: "memory")
#define WAIT2() asm volatile("s_waitcnt vmcnt(2)" ::: "memory")
#define WAIT0() asm volatile("s_waitcnt vmcnt(0)" ::: "memory")
#define LGKM0() asm volatile("s_waitcnt lgkmcnt(0)" ::: "memory")

// ---------------- dtype sniff ----------------
__global__ void sniff_kernel(const u16* __restrict__ raw, int* __restrict__ flag)
{
    if (threadIdx.x == 0 && blockIdx.x == 0) {
        int ok = 1;
        for (int i = 0; i < 32; i++) {
            u16 u = raw[i];
            int e = (u >> 7) & 0xFF;
            if (!(u == 0 || (e >= 90 && e <= 140))) ok = 0;
        }
        *flag = ok;
    }
}

// ---------------- single-launch ingest ----------------
struct IngestArgs { const void* src[20]; int off[21]; };
__global__ __launch_bounds__(256) void ingest_all(
    IngestArgs a, float* __restrict__ dst, const int* __restrict__ flag, int tot)
{
    int gid = blockIdx.x * 256 + threadIdx.x;
    if (gid >= tot) return;
    int lo = 0, hi = 20;
    while (hi - lo > 1) { int mid = (lo + hi) >> 1; if (gid >= a.off[mid]) lo = mid; else hi = mid; }
    int local = gid - a.off[lo];
    if (*flag) dst[gid] = bf2f(((const u16*)a.src[lo])[local]);
    else       dst[gid] = ((const float*)a.src[lo])[local];
}

// ---------------- weight packing ----------------
__global__ __launch_bounds__(256) void pack_qkv(
    const float* __restrict__ wq, const float* __restrict__ wk, const float* __restrict__ wv,
    const float* __restrict__ bq, const float* __restrict__ bk, const float* __restrict__ bv,
    u16* __restrict__ wT, float* __restrict__ bT)
{
    int l = blockIdx.y;
    int idx = blockIdx.x * 256 + threadIdx.x;
    int n = idx >> 8, k = idx & 255;
    const float* w = (n < 256) ? wq : (n < 512) ? wk : wv;
    int nn = n & 255;
    wT[(size_t)l * 768 * 256 + idx] = f2bf(w[(size_t)l * 65536 + k * 256 + nn]);
    if (idx < 768) {
        const float* bb = (idx < 256) ? bq : (idx < 512) ? bk : bv;
        bT[l * 768 + idx] = bb[l * 256 + (idx & 255)];
    }
}

__global__ __launch_bounds__(256) void pack_t(
    const float* __restrict__ src, u16* __restrict__ dst, int R, int C)
{
    int l = blockIdx.y;
    int idx = blockIdx.x * 256 + threadIdx.x;
    int c = idx / R, r = idx % R;
    size_t base = (size_t)l * R * C;
    dst[base + idx] = f2bf(src[base + (size_t)r * C + c]);
}

// ---------------- embedding + fused layer-0 LN1 ----------------
__global__ __launch_bounds__(256) void embed_ln(
    const int* __restrict__ ids, const float* __restrict__ emb,
    const float* __restrict__ g, const float* __restrict__ b,
    float* __restrict__ x, u16* __restrict__ h)
{
    int t = blockIdx.x * 256 + threadIdx.x;
    int row = t >> 6, c = (t & 63) * 4;
    int id = ids[row];
    float4 e = *(const float4*)(emb + (size_t)id * 256 + c);
    *(float4*)(x + (size_t)row * 256 + c) = e;
    float s = e.x + e.y + e.z + e.w;
    float s2 = e.x * e.x + e.y * e.y + e.z * e.z + e.w * e.w;
    #pragma unroll
    for (int mk = 1; mk < 64; mk <<= 1) {
        s += __shfl_xor(s, mk, 64);
        s2 += __shfl_xor(s2, mk, 64);
    }
    float mean = s * (1.f / 256.f);
    float var = s2 * (1.f / 256.f) - mean * mean;
    float rstd = rsqrtf(var + 1e-5f);
    float4 gg = *(const float4*)(g + c);
    float4 bb = *(const float4*)(b + c);
    union { unsigned long long u; u16 q[4]; } oo;
    oo.q[0] = f2bf((e.x - mean) * rstd * gg.x + bb.x);
    oo.q[1] = f2bf((e.y - mean) * rstd * gg.y + bb.y);
    oo.q[2] = f2bf((e.z - mean) * rstd * gg.z + bb.z);
    oo.q[3] = f2bf((e.w - mean) * rstd * gg.w + bb.w);
    *(unsigned long long*)(h + (size_t)row * 256 + c) = oo.u;
}

// ---------------- GEMM: 128x128 tile, BK=64, raw-barrier double-buffered DMA ----------------
// Session-final form (R11-measured, best total 960.4 us). BK=64 halves main-loop
// barrier-events vs BK=32 (small but real win); LDS 64 KB -> 2 blocks/CU (benign per R4).
// Each 32-sub-chunk keeps the proven byte-identical layout; counted WAIT8 one phase ahead.
template <int EPI, int K>
__global__ __launch_bounds__(256, 2) void gemm_db(
    const u16* __restrict__ A, const u16* __restrict__ Bt, const float* __restrict__ bias,
    u16* __restrict__ outB, float* __restrict__ resid, int N)
{
    __shared__ u16 lds[32768];   // 64 KB: BUF0 0..16383 (A 0..8191 | B 8192..16383), BUF1 +16384
    constexpr int NC = K / 64;
    int tid = threadIdx.x, lane = tid & 63, wave = tid >> 6;
    int col = lane & 15, quad = lane >> 4;
    int wm = (wave >> 1) * 64, wn = (wave & 1) * 64;
    int bm = blockIdx.x * 128, bn = blockIdx.y * 128;

    int rL = wave * 32 + (lane >> 2);
    int sx = (lane & 3) ^ ((lane >> 2) & 3);
    const u16* srcA0 = A + (size_t)(bm + rL) * K + sx * 8;
    const u16* srcB0 = Bt + (size_t)(bn + rL) * K + sx * 8;
    int st = wave * 1024 + lane * 8;

    int g8 = (quad ^ (col & 3)) * 8;
    int aoff = (wm + col) * 32 + g8;
    int boff = (wn + col) * 32 + g8;

    f32x4 z4 = { 0.f, 0.f, 0.f, 0.f };
    f32x4 acc[4][4];
    #pragma unroll
    for (int i = 0; i < 4; i++)
        #pragma unroll
        for (int j = 0; j < 4; j++) acc[i][j] = z4;

    // 64-wide chunk = two 32-sub-chunks, each with the proven gemm_db layout.
    // src col = c*64 + sub*32 + sx*8 ; dst = buf + sub*4096 (+8192 for B) + st
    #define STAGE64(c, BUF) do {                                          \
        const u16* _a = srcA0 + (c) * 64;                                 \
        const u16* _b = srcB0 + (c) * 64;                                 \
        gload_lds16(_a, (BUF) + st);                                      \
        gload_lds16(_a + (size_t)16 * K, (BUF) + st + 512);               \
        gload_lds16(_a + 32, (BUF) + 4096 + st);                          \
        gload_lds16(_a + 32 + (size_t)16 * K, (BUF) + 4096 + st + 512);   \
        gload_lds16(_b, (BUF) + 8192 + st);                               \
        gload_lds16(_b + (size_t)16 * K, (BUF) + 8192 + st + 512);        \
        gload_lds16(_b + 32, (BUF) + 12288 + st);                         \
        gload_lds16(_b + 32 + (size_t)16 * K, (BUF) + 12288 + st + 512);  \
    } while (0)

    #define CHUNK64(BUF) do {                                             \
        _Pragma("unroll")                                                 \
        for (int ks = 0; ks < 2; ks++) {                                  \
            bf16x8 af[4], bfv[4];                                         \
            _Pragma("unroll")                                             \
            for (int i = 0; i < 4; i++) af[i] = ld_frag((BUF) + ks * 4096 + aoff + i * 512); \
            _Pragma("unroll")                                             \
            for (int j = 0; j < 4; j++) bfv[j] = ld_frag((BUF) + 8192 + ks * 4096 + boff + j * 512); \
            _Pragma("unroll")                                             \
            for (int i = 0; i < 4; i++)                                   \
                _Pragma("unroll")                                         \
                for (int j = 0; j < 4; j++)                               \
                    acc[i][j] = __builtin_amdgcn_mfma_f32_16x16x32_bf16(af[i], bfv[j], acc[i][j], 0, 0, 0); \
        }                                                                 \
    } while (0)

    u16* BUF0 = lds;
    u16* BUF1 = lds + 16384;
    STAGE64(0, BUF0);
    #pragma unroll
    for (int c = 0; c < NC; ++c) {
        u16* cur = (c & 1) ? BUF1 : BUF0;
        u16* nxt = (c & 1) ? BUF0 : BUF1;
        if (c + 1 < NC) { STAGE64(c + 1, nxt); WAIT8(); }
        else WAIT0();
        BAR();                               // chunk c resident for all waves
        CHUNK64(cur);
        LGKM0(); BAR();                      // all reads of cur complete; re-stageable
    }
    __syncthreads();

    if (EPI == 2) {
        float* Cf = (float*)lds;
        #pragma unroll
        for (int h = 0; h < 2; h++) {
            if ((wave & 1) == h) {
                #pragma unroll
                for (int j = 0; j < 4; j++) {
                    float bv = bias[bn + wn + j * 16 + col];
                    #pragma unroll
                    for (int i = 0; i < 4; i++) {
                        int rl = wm + i * 16 + quad * 4;
                        #pragma unroll
                        for (int r = 0; r < 4; r++)
                            Cf[(rl + r) * 68 + j * 16 + col] = acc[i][j][r] + bv;
                    }
                }
            }
            LGKM0(); BAR();
            #pragma unroll
            for (int u = 0; u < 8; u++) {
                int row = u * 16 + (tid >> 4);
                int cseg = (tid & 15) * 4;
                float* rp = resid + (size_t)(bm + row) * N + bn + h * 64 + cseg;
                const float* cp = Cf + row * 68 + cseg;
                float4 rv = *(float4*)rp;
                float4 cv = *(const float4*)cp;
                rv.x += cv.x; rv.y += cv.y; rv.z += cv.z; rv.w += cv.w;
                *(float4*)rp = rv;
            }
            LGKM0(); BAR();
        }
    } else {
        u16* Cs = lds;
        #pragma unroll
        for (int j = 0; j < 4; j++) {
            int ccl = wn + j * 16 + col;
            float bv = bias[bn + ccl];
            #pragma unroll
            for (int i = 0; i < 4; i++) {
                int rl = wm + i * 16 + quad * 4;
                #pragma unroll
                for (int r = 0; r < 4; r++) {
                    float v = acc[i][j][r] + bv;
                    if (EPI == 1) v = gelu_f(v);
                    Cs[(rl + r) * 136 + ccl] = f2bf(v);
                }
            }
        }
        __syncthreads();
        #pragma unroll
        for (int u = 0; u < 8; u++) {
            int row = u * 16 + (tid >> 4);
            int c8 = (tid & 15) * 8;
            u16* op = outB + (size_t)(bm + row) * N + bn + c8;
            *(uint4*)op = *(const uint4*)(Cs + row * 136 + c8);
        }
    }
    #undef STAGE64
    #undef CHUNK64
}

// ---------------- fused LN2+MLP with producer/consumer wave specialization + T5 ----------------
// (R10/R11-measured ~102 us.)
template <int FUSE>
__global__ __launch_bounds__(512, 2) void mlp2s(
    const float* __restrict__ xin, const u16* __restrict__ w1T, const u16* __restrict__ w2T,
    const float* __restrict__ gamma, const float* __restrict__ beta,
    const float* __restrict__ b1, const float* __restrict__ b2, float* __restrict__ xr,
    const float* __restrict__ g1n, const float* __restrict__ b1n, u16* __restrict__ hout)
{
    __shared__ u16 L[77824];
    int tid = threadIdx.x, lane = tid & 63, wave = tid >> 6;
    int col = lane & 15, quad = lane >> 4;
    int g8 = (quad ^ (col & 3)) * 8;
    int bm = blockIdx.x * 128;
    int isProd = (wave < 4);
    int pw = wave & 3;

    {
        int sub = tid & 7, rsel = tid >> 3;
        float4 g4[8], b4[8];
        #pragma unroll
        for (int q = 0; q < 8; q++) {
            g4[q] = *(const float4*)(gamma + sub * 32 + q * 4);
            b4[q] = *(const float4*)(beta  + sub * 32 + q * 4);
        }
        #pragma unroll
        for (int p = 0; p < 2; p++) {
            int row = p * 64 + rsel;
            const float* xp = xin + (size_t)(bm + row) * 256 + sub * 32;
            float4 v4[8];
            #pragma unroll
            for (int q = 0; q < 8; q++) v4[q] = *(const float4*)(xp + q * 4);
            float s1 = 0.f, s2 = 0.f;
            #pragma unroll
            for (int q = 0; q < 8; q++) {
                s1 += v4[q].x + v4[q].y + v4[q].z + v4[q].w;
                s2 += v4[q].x * v4[q].x + v4[q].y * v4[q].y
                    + v4[q].z * v4[q].z + v4[q].w * v4[q].w;
            }
            s1 += __shfl_xor(s1, 1, 64); s2 += __shfl_xor(s2, 1, 64);
            s1 += __shfl_xor(s1, 2, 64); s2 += __shfl_xor(s2, 2, 64);
            s1 += __shfl_xor(s1, 4, 64); s2 += __shfl_xor(s2, 4, 64);
            float mean = s1 * (1.f / 256.f);
            float var  = s2 * (1.f / 256.f) - mean * mean;
            float rstd = rsqrtf(var + 1e-5f);
            #pragma unroll
            for (int j = 0; j < 4; j++) {
                float4 a = v4[2 * j], c = v4[2 * j + 1];
                float4 ga = g4[2 * j], gc = g4[2 * j + 1];
                float4 ba = b4[2 * j], bc = b4[2 * j + 1];
                union { uint4 u; u16 q[8]; } pkv;
                pkv.q[0] = f2bf((a.x - mean) * rstd * ga.x + ba.x);
                pkv.q[1] = f2bf((a.y - mean) * rstd * ga.y + ba.y);
                pkv.q[2] = f2bf((a.z - mean) * rstd * ga.z + ba.z);
                pkv.q[3] = f2bf((a.w - mean) * rstd * ga.w + ba.w);
                pkv.q[4] = f2bf((c.x - mean) * rstd * gc.x + bc.x);
                pkv.q[5] = f2bf((c.y - mean) * rstd * gc.y + bc.y);
                pkv.q[6] = f2bf((c.z - mean) * rstd * gc.z + bc.z);
                pkv.q[7] = f2bf((c.w - mean) * rstd * gc.w + bc.w);
                *(uint4*)(L + sub * 4096 + row * 32 + ((j ^ (row & 3)) * 8)) = pkv.u;
            }
        }
        float2 bv = *(const float2*)(b1 + tid * 2);
        *(float2*)((float*)(L + 75776) + tid * 2) = bv;
    }

    #define STAGE_W1(ff, base) do {                                                  \
        _Pragma("unroll")                                                            \
        for (int gg = 0; gg < 2; gg++) {                                             \
            int u_ = gg * 512 + tid;                                                 \
            int ks_ = u_ >> 7, rowf_ = (u_ & 127) >> 2, s_ = u_ & 3;                 \
            gload_lds16(w1T + (size_t)((ff) * 32 + rowf_) * 256 + ks_ * 32           \
                            + ((s_ ^ (rowf_ & 3)) * 8),                              \
                        L + (base) + u_ * 8);                                        \
        }                                                                            \
    } while (0)

    #define STAGE_W2(ff, base) do {                                                  \
        _Pragma("unroll")                                                            \
        for (int gg = 0; gg < 2; gg++) {                                             \
            int u_ = gg * 512 + tid;                                                 \
            int d_ = u_ >> 2, s_ = u_ & 3;                                           \
            gload_lds16(w2T + (size_t)d_ * 1024 + (ff) * 32 + ((s_ ^ (d_ & 3)) * 8), \
                        L + (base) + u_ * 8);                                        \
        }                                                                            \
    } while (0)

    STAGE_W1(0, 32768);
    WAIT0(); LGKM0(); BAR();

    f32x4 z4 = { 0.f, 0.f, 0.f, 0.f };
    f32x4 acc2[2][16];
    #pragma unroll
    for (int mt = 0; mt < 2; mt++)
        #pragma unroll
        for (int nt = 0; nt < 16; nt++) acc2[mt][nt] = z4;
    const float* b1l = (const float*)(L + 75776);

    #pragma unroll 2
    for (int f = 0; f < 32; ++f) {
        int pc = f & 1, pn = pc ^ 1;
        if (f < 31) STAGE_W1(f + 1, 32768 + pn * 8192);
        STAGE_W2(f, 49152 + pc * 8192);
        if (f == 31) WAIT2(); else WAIT4();
        BAR();

        if (isProd) {
            const u16* w1b = L + 32768 + pc * 8192;
            f32x4 a1[2][2];
            a1[0][0] = z4; a1[0][1] = z4; a1[1][0] = z4; a1[1][1] = z4;
            __builtin_amdgcn_s_setprio(1);
            #pragma unroll
            for (int ks = 0; ks < 8; ks++) {
                bf16x8 hf0 = ld_frag(L + ks * 4096 + (pw * 32 + col) * 32 + g8);
                bf16x8 hf1 = ld_frag(L + ks * 4096 + (pw * 32 + 16 + col) * 32 + g8);
                #pragma unroll
                for (int kt = 0; kt < 2; kt++) {
                    bf16x8 wf = ld_frag(w1b + ks * 1024 + (kt * 16 + col) * 32 + g8);
                    a1[0][kt] = __builtin_amdgcn_mfma_f32_16x16x32_bf16(wf, hf0, a1[0][kt], 0, 0, 0);
                    a1[1][kt] = __builtin_amdgcn_mfma_f32_16x16x32_bf16(wf, hf1, a1[1][kt], 0, 0, 0);
                }
            }
            __builtin_amdgcn_s_setprio(0);
            u16* gd = L + 65536 + pc * 5120;
            #pragma unroll
            for (int mt = 0; mt < 2; mt++)
                #pragma unroll
                for (int kt = 0; kt < 2; kt++) {
                    float4 bv = *(const float4*)(b1l + f * 32 + kt * 16 + quad * 4);
                    float p0 = gelu_f(a1[mt][kt][0] + bv.x);
                    float p1 = gelu_f(a1[mt][kt][1] + bv.y);
                    float p2 = gelu_f(a1[mt][kt][2] + bv.z);
                    float p3 = gelu_f(a1[mt][kt][3] + bv.w);
                    uint2 w; w.x = pk2(p0, p1); w.y = pk2(p2, p3);
                    *(uint2*)(gd + (pw * 32 + mt * 16 + col) * 40 + kt * 16 + quad * 4) = w;
                }
        } else if (f > 0) {
            const u16* gs = L + 65536 + pn * 5120;
            const u16* w2b = L + 49152 + pn * 8192;
            __builtin_amdgcn_s_setprio(1);
            bf16x8 gf0 = ld_frag(gs + (pw * 32 + col) * 40 + quad * 8);
            bf16x8 gf1 = ld_frag(gs + (pw * 32 + 16 + col) * 40 + quad * 8);
            #pragma unroll
            for (int nt = 0; nt < 16; nt++) {
                bf16x8 wf2 = ld_frag(w2b + (nt * 16 + col) * 32 + g8);
                acc2[0][nt] = __builtin_amdgcn_mfma_f32_16x16x32_bf16(gf0, wf2, acc2[0][nt], 0, 0, 0);
                acc2[1][nt] = __builtin_amdgcn_mfma_f32_16x16x32_bf16(gf1, wf2, acc2[1][nt], 0, 0, 0);
            }
            __builtin_amdgcn_s_setprio(0);
        }
        LGKM0(); BAR();
    }

    WAIT0();
    if (!isProd) {
        const u16* gs = L + 65536 + 5120;
        const u16* w2b = L + 49152 + 8192;
        __builtin_amdgcn_s_setprio(1);
        bf16x8 gf0 = ld_frag(gs + (pw * 32 + col) * 40 + quad * 8);
        bf16x8 gf1 = ld_frag(gs + (pw * 32 + 16 + col) * 40 + quad * 8);
        #pragma unroll
        for (int nt = 0; nt < 16; nt++) {
            bf16x8 wf2 = ld_frag(w2b + (nt * 16 + col) * 32 + g8);
            acc2[0][nt] = __builtin_amdgcn_mfma_f32_16x16x32_bf16(gf0, wf2, acc2[0][nt], 0, 0, 0);
            acc2[1][nt] = __builtin_amdgcn_mfma_f32_16x16x32_bf16(gf1, wf2, acc2[1][nt], 0, 0, 0);
        }
        __builtin_amdgcn_s_setprio(0);

        float b2v[16], g1v[16], b1v[16];
        #pragma unroll
        for (int nt = 0; nt < 16; nt++) {
            b2v[nt] = b2[nt * 16 + col];
            if (FUSE) { g1v[nt] = g1n[nt * 16 + col]; b1v[nt] = b1n[nt * 16 + col]; }
        }
        #pragma unroll
        for (int mt = 0; mt < 2; mt++)
            #pragma unroll
            for (int r = 0; r < 4; r++) {
                int m = pw * 32 + mt * 16 + quad * 4 + r;
                float* xrow = xr + (size_t)(bm + m) * 256;
                float s1 = 0.f, s2 = 0.f;
                #pragma unroll
                for (int nt = 0; nt < 16; nt++) {
                    float xv = xrow[nt * 16 + col] + acc2[mt][nt][r] + b2v[nt];
                    acc2[mt][nt][r] = xv;
                    s1 += xv; s2 += xv * xv;
                }
                #pragma unroll
                for (int nt = 0; nt < 16; nt++) xrow[nt * 16 + col] = acc2[mt][nt][r];
                if (FUSE) {
                    s1 += __shfl_xor(s1, 1, 64); s2 += __shfl_xor(s2, 1, 64);
                    s1 += __shfl_xor(s1, 2, 64); s2 += __shfl_xor(s2, 2, 64);
                    s1 += __shfl_xor(s1, 4, 64); s2 += __shfl_xor(s2, 4, 64);
                    s1 += __shfl_xor(s1, 8, 64); s2 += __shfl_xor(s2, 8, 64);
                    float mean = s1 * (1.f / 256.f);
                    float var  = s2 * (1.f / 256.f) - mean * mean;
                    float rstd = rsqrtf(var + 1e-5f);
                    #pragma unroll
                    for (int nt = 0; nt < 16; nt++)
                        L[m * 256 + nt * 16 + col] =
                            f2bf((acc2[mt][nt][r] - mean) * rstd * g1v[nt] + b1v[nt]);
                }
            }
    }
    if (FUSE) {
        LGKM0(); BAR();
        #pragma unroll
        for (int i = 0; i < 8; i++) {
            int flat = i * 4096 + tid * 8;
            *(uint4*)(hout + (size_t)bm * 256 + flat) = *(const uint4*)(L + flat);
        }
    }
    #undef STAGE_W1
    #undef STAGE_W2
}

// ---------------- sliding-window attention, S^T formulation ----------------
__global__ __launch_bounds__(256, 3) void attn_kernel(
    const u16* __restrict__ qkv, u16* __restrict__ attno)
{
    __shared__ u16 Ks[64 * 72];
    __shared__ u16 Vt[64 * 68];
    __shared__ u16 Ps[4 * 16 * 72];
    int g = blockIdx.x;
    int xc = g & 7, t = g >> 3;
    int r12 = t & 15, s8 = t >> 4;
    int ng = s8 * 8 + xc;
    int bb = ng >> 4, nn = ng & 15;
    int hh = r12 & 3, t2 = r12 >> 2;
    int tid = threadIdx.x, lane = tid & 63, wave = tid >> 6;
    int q16 = lane & 15, quad = lane >> 4;
    float slope = exp2f(-2.f * (float)(hh + 1));
    float slopeL = slope * 1.44269504f;
    const float C1 = 0.125f * 1.44269504f;

    int qt0 = t2 * 2;
    size_t tok0 = (size_t)bb * 8192 + nn * 512;

    bf16x8 bqf[2][2];
    {
        int qrow = t2 * 128 + wave * 16 + q16;
        const u16* qp = qkv + (tok0 + qrow) * 768 + hh * 64 + quad * 8;
        bqf[0][0] = ld_frag(qp);
        bqf[0][1] = ld_frag(qp + 32);
        const u16* qp1 = qp + (size_t)64 * 768;
        bqf[1][0] = ld_frag(qp1);
        bqf[1][1] = ld_frag(qp1 + 32);
    }

    f32x4 z4 = { 0.f, 0.f, 0.f, 0.f };
    f32x4 oa[2][4];
    #pragma unroll
    for (int s = 0; s < 2; s++)
        #pragma unroll
        for (int dt = 0; dt < 4; dt++) oa[s][dt] = z4;
    float lsum[2] = { 0.f, 0.f };
    u16* Psw = Ps + wave * (16 * 72);

    int c_lo = (nn == 0) ? 8 : qt0;
    int c_hi = qt0 + 9;

    int kkK = tid >> 3, c8k = (tid & 7) * 8;
    int kk2 = (tid & 31) * 2, c8v = (tid >> 5) * 8;

    uint4 pk0, pk1, pv0, pv1;
    auto load_c = [&](int c) {
        int tok = (int)tok0 - 512 + c * 64;
        const u16* bK = qkv + (size_t)(tok + kkK) * 768 + hh * 64 + 256 + c8k;
        pk0 = *(const uint4*)bK;
        pk1 = *(const uint4*)(bK + (size_t)32 * 768);
        const u16* bV = qkv + (size_t)(tok + kk2) * 768 + hh * 64 + 512 + c8v;
        pv0 = *(const uint4*)bV;
        pv1 = *(const uint4*)(bV + 768);
    };
    load_c(c_lo);

    for (int c = c_lo; c <= c_hi; ++c) {
        LGKM0(); BAR();
        *(uint4*)(Ks + kkK * 72 + c8k) = pk0;
        *(uint4*)(Ks + (kkK + 32) * 72 + c8k) = pk1;
        {
            union { uint4 u; u16 s[8]; } a, b;
            a.u = pv0; b.u = pv1;
            #pragma unroll
            for (int j = 0; j < 8; j++) {
                unsigned w = (unsigned)a.s[j] | ((unsigned)b.s[j] << 16);
                *(unsigned*)(Vt + (c8v + j) * 68 + kk2) = w;
            }
        }
        if (c < c_hi) load_c(c + 1);
        LGKM0(); BAR();

        bf16x8 kf[4][2];
        #pragma unroll
        for (int kt = 0; kt < 4; kt++)
            #pragma unroll
            for (int ks = 0; ks < 2; ks++)
                kf[kt][ks] = ld_frag(Ks + (kt * 16 + q16) * 72 + ks * 32 + quad * 8);
        bf16x8 vf[4][2];
        #pragma unroll
        for (int dt = 0; dt < 4; dt++)
            #pragma unroll
            for (int ks = 0; ks < 2; ks++) {
                union { uint2 p[2]; bf16x8 b; } cv;
                const u16* vp = Vt + (dt * 16 + q16) * 68 + ks * 32 + quad * 8;
                cv.p[0] = *(const uint2*)(vp);
                cv.p[1] = *(const uint2*)(vp + 4);
                vf[dt][ks] = cv.b;
            }

        int act0 = (c <= qt0 + 8);
        int act1 = (c >= qt0 + 1);
        #pragma unroll
        for (int s = 0; s < 2; s++) {
            if (s == 0 ? !act0 : !act1) continue;
            f32x4 st[4];
            #pragma unroll
            for (int kt = 0; kt < 4; kt++) {
                f32x4 z = z4;
                #pragma unroll
                for (int ks = 0; ks < 2; ks++)
                    z = __builtin_amdgcn_mfma_f32_16x16x32_bf16(kf[kt][ks], bqf[s][ks], z, 0, 0, 0);
                st[kt] = z;
            }
            int qg = t2 * 128 + s * 64 + wave * 16 + q16;
            int D = 512 + qg - c * 64 - quad * 4;
            float nb = -slopeL * (float)D;
            int qts = qt0 + s;
            int diag = (c == qts) || (c == qts + 8);
            float ls = 0.f;
            #pragma unroll
            for (int kt = 0; kt < 4; kt++) {
                float pk[4];
                #pragma unroll
                for (int r = 0; r < 4; r++) {
                    float bias = fmaf(slopeL, (float)(kt * 16 + r), nb);
                    float p = exp2f(fmaf(st[kt][r], C1, bias));
                    if (diag) {
                        int dd = D - (kt * 16 + r);
                        p = ((unsigned)dd <= 512u) ? p : 0.f;
                    }
                    ls += p; pk[r] = p;
                }
                uint2 w;
                w.x = pk2(pk[0], pk[1]);
                w.y = pk2(pk[2], pk[3]);
                *(uint2*)(Psw + q16 * 72 + kt * 16 + quad * 4) = w;
            }
            lsum[s] += ls;
            bf16x8 pf[2];
            #pragma unroll
            for (int ks = 0; ks < 2; ks++)
                pf[ks] = ld_frag(Psw + q16 * 72 + ks * 32 + quad * 8);
            #pragma unroll
            for (int dt = 0; dt < 4; dt++)
                #pragma unroll
                for (int ks = 0; ks < 2; ks++)
                    oa[s][dt] = __builtin_amdgcn_mfma_f32_16x16x32_bf16(pf[ks], vf[dt][ks], oa[s][dt], 0, 0, 0);
        }
    }

    #pragma unroll
    for (int s = 0; s < 2; s++) {
        float lr = lsum[s];
        lr += __shfl_xor(lr, 16, 64);
        lr += __shfl_xor(lr, 32, 64);
        lsum[s] = lr;
    }
    float* lx = (float*)Psw;
    if (quad == 0) { lx[q16] = lsum[0]; lx[16 + q16] = lsum[1]; }
    #pragma unroll
    for (int s = 0; s < 2; s++) {
        float4 lq = *(const float4*)(lx + s * 16 + quad * 4);
        float inv[4] = { 1.f / lq.x, 1.f / lq.y, 1.f / lq.z, 1.f / lq.w };
        int tokb = (int)tok0 + t2 * 128 + s * 64 + wave * 16 + quad * 4;
        #pragma unroll
        for (int r = 0; r < 4; r++)
            #pragma unroll
            for (int dt = 0; dt < 4; dt++)
                attno[(size_t)(tokb + r) * 256 + hh * 64 + dt * 16 + q16] = f2bf(oa[s][dt][r] * inv[r]);
    }
}

// ---------------- LM head with fused final layernorm ----------------
__global__ __launch_bounds__(256) void head_ln_kernel(
    const float* __restrict__ x, const float* __restrict__ g, const float* __restrict__ b,
    const float* __restrict__ hw, const int* __restrict__ flag,
    u16* __restrict__ outb, float* __restrict__ outf)
{
    __shared__ float Wt[14 * 256];
    int tid = threadIdx.x;
    for (int i = tid; i < 14 * 256; i += 256) {
        int v = i >> 8, d = i & 255;
        Wt[i] = hw[d * 14 + v];
    }
    __syncthreads();
    int wave = tid >> 6, lane = tid & 63;
    int row = blockIdx.x * 4 + wave;
    float4 v = *(const float4*)(x + (size_t)row * 256 + lane * 4);
    float s = v.x + v.y + v.z + v.w;
    float s2 = v.x * v.x + v.y * v.y + v.z * v.z + v.w * v.w;
    #pragma unroll
    for (int mk = 1; mk < 64; mk <<= 1) {
        s += __shfl_xor(s, mk, 64);
        s2 += __shfl_xor(s2, mk, 64);
    }
    float mean = s * (1.f / 256.f);
    float var = s2 * (1.f / 256.f) - mean * mean;
    float rstd = rsqrtf(var + 1e-5f);
    int d0 = lane * 4;
    float4 gg = *(const float4*)(g + d0);
    float4 bb = *(const float4*)(b + d0);
    float hv[4];
    hv[0] = (v.x - mean) * rstd * gg.x + bb.x;
    hv[1] = (v.y - mean) * rstd * gg.y + bb.y;
    hv[2] = (v.z - mean) * rstd * gg.z + bb.z;
    hv[3] = (v.w - mean) * rstd * gg.w + bb.w;
    int isbf = *flag;
    for (int vv = 0; vv < 14; vv++) {
        float4 wv4 = *(const float4*)(Wt + vv * 256 + lane * 4);
        float sd = hv[0] * wv4.x + hv[1] * wv4.y + hv[2] * wv4.z + hv[3] * wv4.w;
        #pragma unroll
        for (int mk = 1; mk < 64; mk <<= 1) sd += __shfl_xor(sd, mk, 64);
        if (lane == 0) {
            if (isbf) outb[(size_t)row * 14 + vv] = f2bf(sd);
            else      outf[(size_t)row * 14 + vv] = sd;
        }
    }
}

extern "C" void kernel_launch(void* const* d_in, const int* in_sizes, int n_in,
                              void* d_out, int out_size, void* d_ws, size_t ws_size,
                              hipStream_t stream) {
    (void)out_size; (void)ws_size;
    const int* ids = (const int*)d_in[0];

    char* ws = (char*)d_ws;
    int* flag = (int*)ws; ws += 16;

    IngestArgs ia;
    int off = 0;
    for (int i = 1; i < n_in && i <= 20; i++) {
        ia.src[i - 1] = d_in[i];
        ia.off[i - 1] = off;
        off += in_sizes[i];
    }
    ia.off[20] = off;
    float* fbase = (float*)ws;
    ws += (size_t)((off + 3) & ~3) * 4;
    float* fin[21];
    for (int i = 1; i <= 20; i++) fin[i] = fbase + ia.off[i - 1];

    float* x    = (float*)ws;  ws += (size_t)M_TOK * 256 * 4;
    u16* h      = (u16*)ws;    ws += (size_t)M_TOK * 256 * 2;
    u16* qkv    = (u16*)ws;    ws += (size_t)M_TOK * 768 * 2;
    u16* attno  = (u16*)ws;    ws += (size_t)M_TOK * 256 * 2;
    u16* wqkvT  = (u16*)ws;    ws += (size_t)NLAYER * 768 * 256 * 2;
    u16* woT    = (u16*)ws;    ws += (size_t)NLAYER * 256 * 256 * 2;
    u16* w1T    = (u16*)ws;    ws += (size_t)NLAYER * 1024 * 256 * 2;
    u16* w2T    = (u16*)ws;    ws += (size_t)NLAYER * 256 * 1024 * 2;
    float* bqkv = (float*)ws;  ws += (size_t)NLAYER * 768 * 4;

    sniff_kernel<<<1, 64, 0, stream>>>((const u16*)d_in[1], flag);
    ingest_all<<<(off + 255) / 256, 256, 0, stream>>>(ia, fbase, flag, off);

    pack_qkv<<<dim3(768, NLAYER), 256, 0, stream>>>(fin[2], fin[4], fin[6],
                                                    fin[3], fin[5], fin[7], wqkvT, bqkv);
    pack_t<<<dim3(256, NLAYER), 256, 0, stream>>>(fin[8], woT, 256, 256);
    pack_t<<<dim3(1024, NLAYER), 256, 0, stream>>>(fin[14], w1T, 256, 1024);
    pack_t<<<dim3(1024, NLAYER), 256, 0, stream>>>(fin[16], w2T, 1024, 256);

    embed_ln<<<8192, 256, 0, stream>>>(ids, fin[1], fin[10], fin[11], x, h);

    for (int l = 0; l < NLAYER; ++l) {
        gemm_db<0, 256><<<dim3(256, 6), 256, 0, stream>>>(h, wqkvT + (size_t)l * 768 * 256,
                                                          bqkv + l * 768, qkv, nullptr, 768);
        attn_kernel<<<1024, 256, 0, stream>>>(qkv, attno);
        gemm_db<2, 256><<<dim3(256, 2), 256, 0, stream>>>(attno, woT + (size_t)l * 65536,
                                                          fin[9] + l * 256, nullptr, x, 256);
        if (l < NLAYER - 1) {
            mlp2s<1><<<256, 512, 0, stream>>>(x, w1T + (size_t)l * 262144,
                                              w2T + (size_t)l * 262144,
                                              fin[12] + l * 256, fin[13] + l * 256,
                                              fin[15] + l * 1024, fin[17] + l * 256, x,
                                              fin[10] + (l + 1) * 256, fin[11] + (l + 1) * 256, h);
        } else {
            mlp2s<0><<<256, 512, 0, stream>>>(x, w1T + (size_t)l * 262144,
                                              w2T + (size_t)l * 262144,
                                              fin[12] + l * 256, fin[13] + l * 256,
                                              fin[15] + l * 1024, fin[17] + l * 256, x,
                                              fin[10], fin[11], h);
        }
    }
    head_ln_kernel<<<8192, 256, 0, stream>>>(x, fin[18], fin[19], fin[20], flag,
                                             (u16*)d_out, (float*)d_out);
}